// Round 1
// baseline (262.751 us; speedup 1.0000x reference)
//
#include <hip/hip_runtime.h>
#include <math.h>

#define NB 16
#define NC 64
#define HW 160
#define PLANE (HW * HW)              // 25600
#define SG 161                        // site grid (H+1)
#define NSITES (NB * SG * SG)         // 414736
#define OUT_LD_OFF (NB * NC * PLANE)  // 26214400 (logdet output offset)

// Map local submatrix index -> channel index for the INDS masks.
// n=64: identity. n=32: channels c%4 in {pa,pb}. n=16: c%4 == pa.
__device__ inline int chmap(int i, int n, int pa, int pb) {
    if (n == 64) return i;
    if (n == 32) return ((i >> 1) << 2) | ((i & 1) ? pb : pa);
    return (i << 2) | pa;
}

// One wave factorizes an n x n submatrix of W (LU, partial pivoting) in its
// private LDS region A (n*n floats) and returns log|det|. Wave-lockstep; the
// explicit s_waitcnt drains cross-lane LDS dependencies the compiler can't see.
__device__ float wave_lu_logabsdet(const float* __restrict__ W, float* A,
                                   int n, int sh, int pa, int pb, int lane) {
    for (int e = lane; e < n * n; e += 64) {
        int i = e >> sh, j = e & (n - 1);
        A[e] = W[chmap(i, n, pa, pb) * 64 + chmap(j, n, pa, pb)];
    }
    asm volatile("s_waitcnt lgkmcnt(0) vmcnt(0)" ::: "memory");
    float logdet = 0.f;
    for (int k = 0; k < n; ++k) {
        // --- pivot search over column k (rows >= k), 64-lane max+argmax ---
        float cand = -1.f;
        int idx = k;
        if (lane >= k && lane < n) {
            cand = fabsf(A[(lane << sh) + k]);
            idx = lane;
        }
        for (int off = 32; off; off >>= 1) {
            float oc = __shfl_down(cand, off, 64);
            int oi = __shfl_down(idx, off, 64);
            if (oc > cand) { cand = oc; idx = oi; }
        }
        int p = __shfl(idx, 0, 64);
        // --- swap rows k,p (lane = column) ---
        if (p != k && lane < n) {
            float tk = A[(k << sh) + lane];
            float tp = A[(p << sh) + lane];
            A[(k << sh) + lane] = tp;
            A[(p << sh) + lane] = tk;
        }
        asm volatile("s_waitcnt lgkmcnt(0)" ::: "memory");
        float piv = A[(k << sh) + k];  // broadcast read
        logdet += logf(fabsf(piv));
        float rpiv = 1.f / piv;
        float ckj = (lane < n) ? A[(k << sh) + lane] : 0.f;
        bool act = (lane > k) && (lane < n);
        for (int i2 = k + 1; i2 < n; ++i2) {
            float aik = A[(i2 << sh) + k];  // broadcast read (column k untouched below)
            float mult = aik * rpiv;
            if (act) A[(i2 << sh) + lane] = fmaf(-mult, ckj, A[(i2 << sh) + lane]);
        }
        asm volatile("s_waitcnt lgkmcnt(0)" ::: "memory");
    }
    return logdet;
}

__global__ __launch_bounds__(256) void InvConv1x1GridAlign_kernel(
    const float* __restrict__ x, const float* __restrict__ ld_in,
    const float* __restrict__ W, float* __restrict__ out) {
    __shared__ float A64[64 * 64];
    __shared__ float A32a[32 * 32];
    __shared__ float A32b[32 * 32];
    __shared__ float A16[16 * 16];
    __shared__ float partial[4];

    if (blockIdx.x == 0) {
        // ---- determinant block: 9 slogdets, one wave per matrix group ----
        int wid = threadIdx.x >> 6;
        int lane = threadIdx.x & 63;
        float part = 0.f;
        if (wid == 0) {
            part = 25281.f * wave_lu_logabsdet(W, A64, 64, 6, 0, 0, lane);  // middle: (159*159)
        } else if (wid == 1) {
            part  = wave_lu_logabsdet(W, A32a, 32, 5, 2, 3, lane);  // t: c%4 in {2,3}
            part += wave_lu_logabsdet(W, A32a, 32, 5, 0, 1, lane);  // b: {0,1}
            part *= 159.f;
        } else if (wid == 2) {
            part  = wave_lu_logabsdet(W, A32b, 32, 5, 1, 3, lane);  // l: {1,3}
            part += wave_lu_logabsdet(W, A32b, 32, 5, 0, 2, lane);  // r: {0,2}
            part *= 159.f;
        } else {
            part  = wave_lu_logabsdet(W, A16, 16, 4, 3, 0, lane);  // tl: {3}
            part += wave_lu_logabsdet(W, A16, 16, 4, 2, 0, lane);  // tr: {2}
            part += wave_lu_logabsdet(W, A16, 16, 4, 1, 0, lane);  // bl: {1}
            part += wave_lu_logabsdet(W, A16, 16, 4, 0, 0, lane);  // br: {0}
        }
        if (lane == 0) partial[wid] = part;
        __syncthreads();
        if (threadIdx.x < NB) {
            float dl = partial[0] + partial[1] + partial[2] + partial[3];
            out[OUT_LD_OFF + threadIdx.x] = ld_in[threadIdx.x] + dl;
        }
        return;
    }

    // ---- conv blocks: one thread per site (b, Y, X) on the 161x161 grid ----
    int s = (blockIdx.x - 1) * 256 + threadIdx.x;
    if (s >= NSITES) return;
    unsigned us = (unsigned)s;
    unsigned b = us / (SG * SG);
    unsigned rr = us - b * (SG * SG);
    unsigned uy = rr / SG;
    int Y = (int)uy;
    int X = (int)(rr - uy * SG);

    const float* xb = x + (size_t)b * NC * PLANE;
    float* ob = out + (size_t)b * NC * PLANE;

    // quadrant validity + in-plane pixel offsets (m = 2*ic + jc)
    bool okT = (Y >= 1), okB = (Y <= HW - 1), okL = (X >= 1), okR = (X <= HW - 1);
    bool v00 = okT && okL, v01 = okT && okR, v10 = okB && okL, v11 = okB && okR;
    int off00 = (Y - 1) * HW + (X - 1);
    int off01 = (Y - 1) * HW + X;
    int off10 = Y * HW + (X - 1);
    int off11 = Y * HW + X;

    float u[64];
#pragma unroll
    for (int o = 0; o < 64; ++o) u[o] = 0.f;

#pragma unroll 1  // keep body ~1K FMAs for I$; TLP hides chunk load latency
    for (int cc = 0; cc < 4; ++cc) {
        float v[16];
#pragma unroll
        for (int g4 = 0; g4 < 4; ++g4) {
            // Z-channel c = 4g+m reads input plane 4g+(3-m) (= c^3) at quadrant m
            const float* pg = xb + (size_t)(cc * 4 + g4) * 4 * PLANE;
            v[g4 * 4 + 0] = v00 ? pg[3 * PLANE + off00] : 0.f;
            v[g4 * 4 + 1] = v01 ? pg[2 * PLANE + off01] : 0.f;
            v[g4 * 4 + 2] = v10 ? pg[1 * PLANE + off10] : 0.f;
            v[g4 * 4 + 3] = v11 ? pg[0 * PLANE + off11] : 0.f;
        }
        const float* wc = W + cc * 16;  // wave-uniform -> s_load_dwordx16 expected
#pragma unroll
        for (int o = 0; o < 64; ++o) {
            const float* wr = wc + o * 64;
            float a = u[o];
#pragma unroll
            for (int k = 0; k < 16; ++k) a = fmaf(wr[k], v[k], a);
            u[o] = a;
        }
    }

    // scatter: u[o] -> output plane o^3, quadrant m = o&3 (same offsets as gather)
#pragma unroll
    for (int g = 0; g < 16; ++g) {
        float* pg = ob + (size_t)g * 4 * PLANE;
        if (v00) pg[3 * PLANE + off00] = u[g * 4 + 0];
        if (v01) pg[2 * PLANE + off01] = u[g * 4 + 1];
        if (v10) pg[1 * PLANE + off10] = u[g * 4 + 2];
        if (v11) pg[0 * PLANE + off11] = u[g * 4 + 3];
    }
}

extern "C" void kernel_launch(void* const* d_in, const int* in_sizes, int n_in,
                              void* d_out, int out_size, void* d_ws, size_t ws_size,
                              hipStream_t stream) {
    const float* x = (const float*)d_in[0];
    const float* ld = (const float*)d_in[1];
    const float* W = (const float*)d_in[2];
    float* out = (float*)d_out;
    int nconv = (NSITES + 255) / 256;  // 1621
    hipLaunchKernelGGL(InvConv1x1GridAlign_kernel, dim3(nconv + 1), dim3(256), 0,
                       stream, x, ld, W, out);
}